// Round 16
// baseline (92.926 us; speedup 1.0000x reference)
//
#include <hip/hip_runtime.h>
#include <hip/hip_bf16.h>
#include <hip/hip_fp16.h>
#include <math.h>

typedef __attribute__((ext_vector_type(8))) short bfrag8;      // 8 x bf16
typedef __attribute__((ext_vector_type(8))) _Float16 hfrag8;   // 8 x f16
typedef __attribute__((ext_vector_type(4))) float facc4;
typedef __attribute__((ext_vector_type(16))) float facc16;

#define MFMA16B(a, b, c) __builtin_amdgcn_mfma_f32_16x16x32_bf16((a), (b), (c), 0, 0, 0)
#define MFMA32B(a, b, c) __builtin_amdgcn_mfma_f32_32x32x16_bf16((a), (b), (c), 0, 0, 0)
#define MFMA32H(a, b, c) __builtin_amdgcn_mfma_f32_32x32x16_f16((a), (b), (c), 0, 0, 0)

__device__ __forceinline__ void gload_lds16(const void* g, void* l) {
    __builtin_amdgcn_global_load_lds(
        (const __attribute__((address_space(1))) void*)g,
        (__attribute__((address_space(3))) void*)l, 16, 0, 0);
}

__device__ __forceinline__ unsigned short f2bf(float f) {
    unsigned u = __float_as_uint(f);
    u += 0x7fffu + ((u >> 16) & 1u);
    return (unsigned short)(u >> 16);
}

__device__ __forceinline__ unsigned pk2(float a, float b) {
    auto h = __builtin_amdgcn_cvt_pkrtz(a, b);   // __fp16 ext_vector(2)
    union { decltype(h) h; unsigned u; } c;
    c.h = h;
    return c.u;
}

// -------------------- fused prep kernel --------------------
__device__ __forceinline__ void do_transpose(const float* __restrict__ src,
                                             unsigned short* __restrict__ dst,
                                             int Kdim, int N, int nb, int kb,
                                             float (*tile)[33], int tid) {
    int tx = tid & 31, ty = tid >> 5;
#pragma unroll
    for (int r = ty; r < 32; r += 8)
        tile[r][tx] = src[(size_t)(kb + r) * N + nb + tx];
    __syncthreads();
#pragma unroll
    for (int r = ty; r < 32; r += 8)
        dst[(size_t)(nb + r) * Kdim + kb + tx] = f2bf(tile[tx][r]);
}

__global__ __launch_bounds__(256) void k_prep(
    const float* __restrict__ X, const float* __restrict__ Wq,
    const float* __restrict__ Wk, const float* __restrict__ Wv,
    const float* __restrict__ Wp,
    unsigned short* __restrict__ Xb, unsigned short* __restrict__ Wqkvt,
    unsigned short* __restrict__ Wpt) {
    __shared__ float tile[32][33];
    int blk = blockIdx.x, tid = threadIdx.x;
    if (blk < 4096) {
        int i = (blk * 256 + tid) * 4;
        float4 v = *reinterpret_cast<const float4*>(X + i);
        unsigned short o[4] = {f2bf(v.x), f2bf(v.y), f2bf(v.z), f2bf(v.w)};
        *reinterpret_cast<ulonglong1*>(Xb + i) = *reinterpret_cast<ulonglong1*>(o);
    } else if (blk < 5120) {
        int idx = blk - 4096;
        do_transpose(Wq, Wqkvt, 1024, 1024, (idx & 31) * 32, (idx >> 5) * 32, tile, tid);
    } else if (blk < 5376) {
        int idx = blk - 5120;
        do_transpose(Wk, Wqkvt + 1024 * 1024, 1024, 256, (idx & 7) * 32, (idx >> 3) * 32, tile, tid);
    } else if (blk < 5632) {
        int idx = blk - 5376;
        do_transpose(Wv, Wqkvt + 1280 * 1024, 1024, 256, (idx & 7) * 32, (idx >> 3) * 32, tile, tid);
    } else {
        int idx = blk - 5632;
        do_transpose(Wp, Wpt, 1024, 1024, (idx & 31) * 32, (idx >> 5) * 32, tile, tid);
    }
}

// -------------------- GEMM: C = A[M][K] * Bt[N][K]^T, 128x64 tile, 8 waves -------------
// (R11 config — best measured: 512 threads, wave tile 32x32, grids 24x32 / 16x32)
template <int EPI>
__global__ __launch_bounds__(512) void k_gemm_bt(
    const unsigned short* __restrict__ A, const unsigned short* __restrict__ Bt,
    int M, int N, int K,
    unsigned short* __restrict__ Qo, unsigned short* __restrict__ Ko,
    unsigned short* __restrict__ Vto,
    const float* __restrict__ Xres, float* __restrict__ Out) {
    __shared__ char lds[49152];
    const int tid = threadIdx.x;
    const int lane = tid & 63, wid = tid >> 6;
    const int wr = wid >> 1, wc = wid & 1;
    const int l15 = lane & 15, lhi = lane >> 4;
    const int m0 = blockIdx.y * 128, n0 = blockIdx.x * 64;
    const int nk = K >> 6;

    facc4 acc[2][2] = {};

    auto STAGE = [&](int buf, int k0) {
#pragma unroll
        for (int i = 0; i < 2; ++i) {
            int p = (wid * 2 + i) * 1024 + lane * 16;
            int row = p >> 7;
            int src = (p & 127) ^ ((row & 7) << 4);
            gload_lds16(A + (size_t)(m0 + row) * K + k0 + (src >> 1),
                        lds + buf * 16384 + (wid * 2 + i) * 1024);
        }
        {
            int p = wid * 1024 + lane * 16;
            int row = p >> 7;
            int src = (p & 127) ^ ((row & 7) << 4);
            gload_lds16(Bt + (size_t)(n0 + row) * K + k0 + (src >> 1),
                        lds + 32768 + buf * 8192 + wid * 1024);
        }
    };

    STAGE(0, 0);
    __syncthreads();

    for (int t = 0; t < nk; ++t) {
        const int cur = t & 1;
        if (t + 1 < nk) STAGE(cur ^ 1, (t + 1) * 64);
        const char* Ab = lds + cur * 16384;
        const char* Bb = lds + 32768 + cur * 8192;
#pragma unroll
        for (int kc = 0; kc < 2; ++kc) {
            bfrag8 af[2], bfv[2];
#pragma unroll
            for (int mi = 0; mi < 2; ++mi) {
                int row = wr * 32 + mi * 16 + l15;
                int off = (row * 128 + kc * 64 + lhi * 16) ^ ((row & 7) << 4);
                af[mi] = *reinterpret_cast<const bfrag8*>(Ab + off);
            }
#pragma unroll
            for (int ni = 0; ni < 2; ++ni) {
                int row = wc * 32 + ni * 16 + l15;
                int off = (row * 128 + kc * 64 + lhi * 16) ^ ((row & 7) << 4);
                bfv[ni] = *reinterpret_cast<const bfrag8*>(Bb + off);
            }
#pragma unroll
            for (int mi = 0; mi < 2; ++mi)
#pragma unroll
                for (int ni = 0; ni < 2; ++ni)
                    acc[mi][ni] = MFMA16B(af[mi], bfv[ni], acc[mi][ni]);
        }
        __syncthreads();
    }

    if (EPI == 0 && n0 >= 1280) {
        unsigned short* VT = (unsigned short*)lds;  // [64 cols][136] f16
#pragma unroll
        for (int mi = 0; mi < 2; ++mi)
#pragma unroll
            for (int ni = 0; ni < 2; ++ni) {
                int col = wc * 32 + ni * 16 + l15;
                int row0 = wr * 32 + mi * 16 + lhi * 4;
                unsigned long long u = 0;
#pragma unroll
                for (int r = 0; r < 4; ++r)
                    u |= (unsigned long long)__half_as_ushort(__float2half(acc[mi][ni][r]))
                         << (16 * r);
                *reinterpret_cast<unsigned long long*>(VT + col * 136 + row0) = u;
            }
        __syncthreads();
        int c = tid >> 3, part = tid & 7;
        int b = m0 >> 11;
        int g = (n0 - 1280) >> 6;
        unsigned short* dstp =
            Vto + ((size_t)(b * 4 + g) * 64 + c) * 2048 + (m0 & 2047) + part * 16;
        const unsigned short* srcp = VT + c * 136 + part * 16;
        *(reinterpret_cast<uint4*>(dstp) + 0) = *(reinterpret_cast<const uint4*>(srcp) + 0);
        *(reinterpret_cast<uint4*>(dstp) + 1) = *(reinterpret_cast<const uint4*>(srcp) + 1);
        return;
    }

#pragma unroll
    for (int mi = 0; mi < 2; ++mi)
#pragma unroll
        for (int ni = 0; ni < 2; ++ni)
#pragma unroll
            for (int r = 0; r < 4; ++r) {
                int grow = m0 + wr * 32 + mi * 16 + lhi * 4 + r;
                int gcol = n0 + wc * 32 + ni * 16 + l15;
                float v = acc[mi][ni][r];
                if (EPI == 0) {
                    int b = grow >> 11, t = grow & 2047;
                    if (gcol < 1024) {
                        Qo[(size_t)grow * 1024 + gcol] = f2bf(v * 0.18033688f);  // /8 * log2e
                    } else {
                        int cc = gcol - 1024;
                        int g = cc >> 6, e = cc & 63;
                        Ko[(((size_t)(b * 4 + g) * 2048 + t) << 6) + e] = f2bf(v);
                    }
                } else {
                    size_t idx = (size_t)grow * 1024 + gcol;
                    Out[idx] = Xres[idx] + v;
                }
            }
}

// -------------------- flash attention: 32 waves/CU (8/SIMD) via 1024-thread blocks -----
// 512 blocks (XCD-swizzled) x 1024 threads = 16 waves: (kvh = wid>>2 in 0..3, qw = wid&3).
// Wave: 32 q rows x 512 keys (its quarter), KVBLK=32, 16 steps, double-buffered.
// LDS 64KB: K [kvh][dbuf][4KB] @0 (32KB), V [kvh][dbuf][4KB] @32768 (32KB).
// 2 blocks/CU x 16 waves = 32 waves/CU = 8/SIMD (2x all previous variants; VGPR cap 64,
// same as the measured-no-spill R5/R9 kernels). Inner loop identical to R10's.
__global__ __launch_bounds__(1024, 2) void k_attn(
    const unsigned short* __restrict__ Q,    // [4096][1024] bf16, pre-scaled by 0.125*log2e
    const unsigned short* __restrict__ Kb,   // [8][2048][64] bf16
    const unsigned short* __restrict__ Vt,   // [8][64][2048] f16
    unsigned short* __restrict__ Abuf) {     // [4096][1024] bf16
    __shared__ char smem[65536];

    const int tid = threadIdx.x;
    const int lane = tid & 63, wid = tid >> 6;
    const int kvh = wid >> 2, qw = wid & 3;
    const int l31 = lane & 31, hi = lane >> 5;

    int wg = blockIdx.x;
    int swz = ((wg & 7) << 6) | (wg >> 3);   // XCD-aware (512 % 8 == 0)
    const int qt = swz & 15, head = (swz >> 4) & 15, b = swz >> 8;
    const int g = head >> 2;
    const size_t kvK = (size_t)(b * 4 + g) * 2048 * 64;
    const size_t kvV = (size_t)(b * 4 + g) * 64 * 2048;
    const int qrow0 = b * 2048 + qt * 128 + qw * 32;

    // Q fragments (B-operand): B[k = hi*8+j][col = q = l31], 32 q rows
    bfrag8 qf[4];
#pragma unroll
    for (int ks = 0; ks < 4; ++ks)
        qf[ks] = *reinterpret_cast<const bfrag8*>(
            Q + (size_t)(qrow0 + l31) * 1024 + head * 64 + ks * 16 + hi * 8);

    // staging: per step each wave loads 1KB of K + 1KB of V of its kvh quarter.
    // K tile [32 kv][64 d] bf16 (4KB, 128B rows, 8-slot XOR swz);
    // V tile [64 d][32 kv] f16 (4KB, 64B rows, 2-bit XOR swz).
    const int p = qw * 1024 + lane * 16;
    const int rK = p >> 7;
    const int cK = (p & 127) ^ ((rK & 7) << 4);
    const unsigned short* srcK = Kb + kvK + (size_t)(kvh * 512 + rK) * 64 + (cK >> 1);
    const int rV = p >> 6;
    const int cV = (p & 63) ^ ((rV & 6) << 3);
    const unsigned short* srcV = Vt + kvV + (size_t)rV * 2048 + kvh * 512 + (cV >> 1);
    const int dK = kvh * 8192 + qw * 1024;           // + cur*4096
    const int dV = 32768 + kvh * 8192 + qw * 1024;   // + cur*4096

    facc16 o[2] = {};
    const facc16 fz = {};
    float psA = 0.f, psB = 0.f;

    // prologue: stage tile 0 into buf 0
    gload_lds16(srcK, smem + dK);
    gload_lds16(srcV, smem + dV);
    __syncthreads();

    for (int t = 0; t < 16; ++t) {
        const int cur = t & 1;
        if (t < 15) {
            gload_lds16(srcK + (size_t)(t + 1) * (32 * 64), smem + dK + (cur ^ 1) * 4096);
            gload_lds16(srcV + (size_t)(t + 1) * 32, smem + dV + (cur ^ 1) * 4096);
        }
        const char* Kc = smem + kvh * 8192 + cur * 4096;
        const char* Vc = smem + 32768 + kvh * 8192 + cur * 4096;

        // S^T = K * Q^T : col = q = l31, row = kv = (r&3) + 8*(r>>2) + 4*hi (32 keys)
        facc16 s;
        __builtin_amdgcn_s_setprio(1);
#pragma unroll
        for (int ks = 0; ks < 4; ++ks) {
            int off = (l31 * 128 + ks * 32 + hi * 16) ^ ((l31 & 7) << 4);
            bfrag8 kf = *reinterpret_cast<const bfrag8*>(Kc + off);
            s = MFMA32B(kf, qf[ks], ks == 0 ? fz : s);
        }
        __builtin_amdgcn_s_setprio(0);

        // p = exp2(s), in-register P^T assembly, PV
#pragma unroll
        for (int e = 0; e < 16; e += 2) {
            float e0 = __builtin_amdgcn_exp2f(s[e]);
            float e1 = __builtin_amdgcn_exp2f(s[e + 1]);
            s[e] = e0;
            s[e + 1] = e1;
            psA += e0;
            psB += e1;
        }
#pragma unroll
        for (int kh = 0; kh < 2; ++kh) {
            const int pb = kh * 2;
            unsigned a0 = pk2(s[4 * pb + 0], s[4 * pb + 1]);
            unsigned a1 = pk2(s[4 * pb + 2], s[4 * pb + 3]);
            unsigned b0 = pk2(s[4 * pb + 4], s[4 * pb + 5]);
            unsigned b1 = pk2(s[4 * pb + 6], s[4 * pb + 7]);
            asm("v_permlane32_swap_b32 %0, %1" : "+v"(a0), "+v"(b0));
            asm("v_permlane32_swap_b32 %0, %1" : "+v"(a1), "+v"(b1));
            union { unsigned u[4]; hfrag8 h; } pu;
            pu.u[0] = a0; pu.u[1] = a1; pu.u[2] = b0; pu.u[3] = b1;
            __builtin_amdgcn_s_setprio(1);
#pragma unroll
            for (int ot = 0; ot < 2; ++ot) {
                int row = ot * 32 + l31;
                int off = row * 64 + ((kh * 32 + hi * 16) ^ ((row & 6) << 3));
                hfrag8 vf = *reinterpret_cast<const hfrag8*>(Vc + off);
                o[ot] = MFMA32H(vf, pu.h, o[ot]);
            }
            __builtin_amdgcn_s_setprio(0);
        }
        __syncthreads();
    }

    // combine 4 kvh partials per qw group, two ot-phases (48KB + 3KB LDS reuse)
    float psum = psA + psB;
    float* cm = (float*)smem;                   // 12 x 1024 f32 = 48KB
    float* cmL = (float*)(smem + 49152);        // 12 x 64 f32 = 3KB
    const int pb12 = (qw * 3 + kvh - 1);        // valid when kvh>0
#pragma unroll
    for (int ot = 0; ot < 2; ++ot) {
        __syncthreads();
        if (kvh) {
#pragma unroll
            for (int r = 0; r < 16; ++r)
                cm[pb12 * 1024 + r * 64 + lane] = o[ot][r];
            if (ot == 0) cmL[pb12 * 64 + lane] = psum;
        }
        __syncthreads();
        if (kvh == 0) {
#pragma unroll
            for (int j = 0; j < 3; ++j) {
                const int bb = (qw * 3 + j) * 1024;
#pragma unroll
                for (int r = 0; r < 16; ++r)
                    o[ot][r] += cm[bb + r * 64 + lane];
                if (ot == 0) psum += cmL[(qw * 3 + j) * 64 + lane];
            }
        }
    }
    if (kvh == 0) {
        float l = psum + __shfl_xor(psum, 32, 64);
        float rl = 1.0f / l;
        int arow = qrow0 + l31;
#pragma unroll
        for (int ot = 0; ot < 2; ++ot)
#pragma unroll
            for (int p2 = 0; p2 < 4; ++p2) {
                unsigned long long u = 0;
#pragma unroll
                for (int r = 0; r < 4; ++r)
                    u |= (unsigned long long)f2bf(o[ot][4 * p2 + r] * rl) << (16 * r);
                *reinterpret_cast<unsigned long long*>(
                    Abuf + (size_t)arow * 1024 + head * 64 + ot * 32 + p2 * 8 + hi * 4) = u;
            }
    }
}

// -------------------- launch --------------------

extern "C" void kernel_launch(void* const* d_in, const int* in_sizes, int n_in,
                              void* d_out, int out_size, void* d_ws, size_t ws_size,
                              hipStream_t stream) {
    const float* X = (const float*)d_in[0];
    const float* Wq = (const float*)d_in[1];
    const float* Wk = (const float*)d_in[2];
    const float* Wv = (const float*)d_in[3];
    const float* Wpost = (const float*)d_in[4];
    float* Out = (float*)d_out;

    unsigned short* Xb = (unsigned short*)d_ws;          // 4096*1024 bf16
    unsigned short* Wqkvt = Xb + 4096 * 1024;            // 1536*1024 bf16
    unsigned short* Wpt = Wqkvt + 1536 * 1024;           // 1024*1024 bf16
    unsigned short* Qb = Wpt + 1024 * 1024;              // 4096*1024 bf16 (pre-scaled)
    unsigned short* Kbuf = Qb + 4096 * 1024;             // 8*2048*64 bf16
    unsigned short* Vtbuf = Kbuf + 8 * 2048 * 64;        // 8*64*2048 f16
    unsigned short* Abuf = Vtbuf + 8 * 2048 * 64;        // 4096*1024 bf16

    k_prep<<<6656, 256, 0, stream>>>(X, Wq, Wk, Wv, Wpost, Xb, Wqkvt, Wpt);

    k_gemm_bt<0><<<dim3(24, 32), 512, 0, stream>>>(Xb, Wqkvt, 4096, 1536, 1024,
                                                   Qb, Kbuf, Vtbuf, nullptr, nullptr);

    k_attn<<<512, 1024, 0, stream>>>(Qb, Kbuf, Vtbuf, Abuf);

    k_gemm_bt<1><<<dim3(16, 32), 512, 0, stream>>>(Abuf, Wpt, 4096, 1024, 1024,
                                                   nullptr, nullptr, nullptr, X, Out);
}

// Round 17
// 88.767 us; speedup vs baseline: 1.0469x; 1.0469x over previous
//
#include <hip/hip_runtime.h>
#include <hip/hip_bf16.h>
#include <hip/hip_fp16.h>
#include <math.h>

typedef __attribute__((ext_vector_type(8))) short bfrag8;      // 8 x bf16
typedef __attribute__((ext_vector_type(8))) _Float16 hfrag8;   // 8 x f16
typedef __attribute__((ext_vector_type(4))) float facc4;
typedef __attribute__((ext_vector_type(16))) float facc16;

#define MFMA16B(a, b, c) __builtin_amdgcn_mfma_f32_16x16x32_bf16((a), (b), (c), 0, 0, 0)
#define MFMA32B(a, b, c) __builtin_amdgcn_mfma_f32_32x32x16_bf16((a), (b), (c), 0, 0, 0)
#define MFMA32H(a, b, c) __builtin_amdgcn_mfma_f32_32x32x16_f16((a), (b), (c), 0, 0, 0)

__device__ __forceinline__ void gload_lds16(const void* g, void* l) {
    __builtin_amdgcn_global_load_lds(
        (const __attribute__((address_space(1))) void*)g,
        (__attribute__((address_space(3))) void*)l, 16, 0, 0);
}

__device__ __forceinline__ unsigned short f2bf(float f) {
    unsigned u = __float_as_uint(f);
    u += 0x7fffu + ((u >> 16) & 1u);
    return (unsigned short)(u >> 16);
}

__device__ __forceinline__ unsigned pk2(float a, float b) {
    auto h = __builtin_amdgcn_cvt_pkrtz(a, b);   // __fp16 ext_vector(2)
    union { decltype(h) h; unsigned u; } c;
    c.h = h;
    return c.u;
}

// -------------------- fused prep kernel --------------------
__device__ __forceinline__ void do_transpose(const float* __restrict__ src,
                                             unsigned short* __restrict__ dst,
                                             int Kdim, int N, int nb, int kb,
                                             float (*tile)[33], int tid) {
    int tx = tid & 31, ty = tid >> 5;
#pragma unroll
    for (int r = ty; r < 32; r += 8)
        tile[r][tx] = src[(size_t)(kb + r) * N + nb + tx];
    __syncthreads();
#pragma unroll
    for (int r = ty; r < 32; r += 8)
        dst[(size_t)(nb + r) * Kdim + kb + tx] = f2bf(tile[tx][r]);
}

__global__ __launch_bounds__(256) void k_prep(
    const float* __restrict__ X, const float* __restrict__ Wq,
    const float* __restrict__ Wk, const float* __restrict__ Wv,
    const float* __restrict__ Wp,
    unsigned short* __restrict__ Xb, unsigned short* __restrict__ Wqkvt,
    unsigned short* __restrict__ Wpt) {
    __shared__ float tile[32][33];
    int blk = blockIdx.x, tid = threadIdx.x;
    if (blk < 4096) {
        int i = (blk * 256 + tid) * 4;
        float4 v = *reinterpret_cast<const float4*>(X + i);
        unsigned short o[4] = {f2bf(v.x), f2bf(v.y), f2bf(v.z), f2bf(v.w)};
        *reinterpret_cast<ulonglong1*>(Xb + i) = *reinterpret_cast<ulonglong1*>(o);
    } else if (blk < 5120) {
        int idx = blk - 4096;
        do_transpose(Wq, Wqkvt, 1024, 1024, (idx & 31) * 32, (idx >> 5) * 32, tile, tid);
    } else if (blk < 5376) {
        int idx = blk - 5120;
        do_transpose(Wk, Wqkvt + 1024 * 1024, 1024, 256, (idx & 7) * 32, (idx >> 3) * 32, tile, tid);
    } else if (blk < 5632) {
        int idx = blk - 5376;
        do_transpose(Wv, Wqkvt + 1280 * 1024, 1024, 256, (idx & 7) * 32, (idx >> 3) * 32, tile, tid);
    } else {
        int idx = blk - 5632;
        do_transpose(Wp, Wpt, 1024, 1024, (idx & 31) * 32, (idx >> 5) * 32, tile, tid);
    }
}

// -------------------- GEMM: C = A[M][K] * Bt[N][K]^T, 128x64 tile, 8 waves -------------
// (R11 config — best measured: 512 threads, wave tile 32x32, grids 24x32 / 16x32)
template <int EPI>
__global__ __launch_bounds__(512) void k_gemm_bt(
    const unsigned short* __restrict__ A, const unsigned short* __restrict__ Bt,
    int M, int N, int K,
    unsigned short* __restrict__ Qo, unsigned short* __restrict__ Ko,
    unsigned short* __restrict__ Vto,
    const float* __restrict__ Xres, float* __restrict__ Out) {
    __shared__ char lds[49152];
    const int tid = threadIdx.x;
    const int lane = tid & 63, wid = tid >> 6;
    const int wr = wid >> 1, wc = wid & 1;
    const int l15 = lane & 15, lhi = lane >> 4;
    const int m0 = blockIdx.y * 128, n0 = blockIdx.x * 64;
    const int nk = K >> 6;

    facc4 acc[2][2] = {};

    auto STAGE = [&](int buf, int k0) {
#pragma unroll
        for (int i = 0; i < 2; ++i) {
            int p = (wid * 2 + i) * 1024 + lane * 16;
            int row = p >> 7;
            int src = (p & 127) ^ ((row & 7) << 4);
            gload_lds16(A + (size_t)(m0 + row) * K + k0 + (src >> 1),
                        lds + buf * 16384 + (wid * 2 + i) * 1024);
        }
        {
            int p = wid * 1024 + lane * 16;
            int row = p >> 7;
            int src = (p & 127) ^ ((row & 7) << 4);
            gload_lds16(Bt + (size_t)(n0 + row) * K + k0 + (src >> 1),
                        lds + 32768 + buf * 8192 + wid * 1024);
        }
    };

    STAGE(0, 0);
    __syncthreads();

    for (int t = 0; t < nk; ++t) {
        const int cur = t & 1;
        if (t + 1 < nk) STAGE(cur ^ 1, (t + 1) * 64);
        const char* Ab = lds + cur * 16384;
        const char* Bb = lds + 32768 + cur * 8192;
#pragma unroll
        for (int kc = 0; kc < 2; ++kc) {
            bfrag8 af[2], bfv[2];
#pragma unroll
            for (int mi = 0; mi < 2; ++mi) {
                int row = wr * 32 + mi * 16 + l15;
                int off = (row * 128 + kc * 64 + lhi * 16) ^ ((row & 7) << 4);
                af[mi] = *reinterpret_cast<const bfrag8*>(Ab + off);
            }
#pragma unroll
            for (int ni = 0; ni < 2; ++ni) {
                int row = wc * 32 + ni * 16 + l15;
                int off = (row * 128 + kc * 64 + lhi * 16) ^ ((row & 7) << 4);
                bfv[ni] = *reinterpret_cast<const bfrag8*>(Bb + off);
            }
#pragma unroll
            for (int mi = 0; mi < 2; ++mi)
#pragma unroll
                for (int ni = 0; ni < 2; ++ni)
                    acc[mi][ni] = MFMA16B(af[mi], bfv[ni], acc[mi][ni]);
        }
        __syncthreads();
    }

    if (EPI == 0 && n0 >= 1280) {
        unsigned short* VT = (unsigned short*)lds;  // [64 cols][136] f16
#pragma unroll
        for (int mi = 0; mi < 2; ++mi)
#pragma unroll
            for (int ni = 0; ni < 2; ++ni) {
                int col = wc * 32 + ni * 16 + l15;
                int row0 = wr * 32 + mi * 16 + lhi * 4;
                unsigned long long u = 0;
#pragma unroll
                for (int r = 0; r < 4; ++r)
                    u |= (unsigned long long)__half_as_ushort(__float2half(acc[mi][ni][r]))
                         << (16 * r);
                *reinterpret_cast<unsigned long long*>(VT + col * 136 + row0) = u;
            }
        __syncthreads();
        int c = tid >> 3, part = tid & 7;
        int b = m0 >> 11;
        int g = (n0 - 1280) >> 6;
        unsigned short* dstp =
            Vto + ((size_t)(b * 4 + g) * 64 + c) * 2048 + (m0 & 2047) + part * 16;
        const unsigned short* srcp = VT + c * 136 + part * 16;
        *(reinterpret_cast<uint4*>(dstp) + 0) = *(reinterpret_cast<const uint4*>(srcp) + 0);
        *(reinterpret_cast<uint4*>(dstp) + 1) = *(reinterpret_cast<const uint4*>(srcp) + 1);
        return;
    }

#pragma unroll
    for (int mi = 0; mi < 2; ++mi)
#pragma unroll
        for (int ni = 0; ni < 2; ++ni)
#pragma unroll
            for (int r = 0; r < 4; ++r) {
                int grow = m0 + wr * 32 + mi * 16 + lhi * 4 + r;
                int gcol = n0 + wc * 32 + ni * 16 + l15;
                float v = acc[mi][ni][r];
                if (EPI == 0) {
                    int b = grow >> 11, t = grow & 2047;
                    if (gcol < 1024) {
                        Qo[(size_t)grow * 1024 + gcol] = f2bf(v * 0.18033688f);  // /8 * log2e
                    } else {
                        int cc = gcol - 1024;
                        int g = cc >> 6, e = cc & 63;
                        Ko[(((size_t)(b * 4 + g) * 2048 + t) << 6) + e] = f2bf(v);
                    }
                } else {
                    size_t idx = (size_t)grow * 1024 + gcol;
                    Out[idx] = Xres[idx] + v;
                }
            }
}

// -------------------- flash attention (R9 kernel, best measured: 44.8 us) --------------
// 512 blocks (XCD-swizzled) x 512 threads = 8 waves: (kvh = wid>>2, qw = wid&3).
// Each wave: 32 q rows, 16 of 32 key tiles (its KV half, interleaved stride-128).
// Softmax: p = exp2(s) (scale*log2e folded into Q; shift-free, cancels in O/l).
__global__ __launch_bounds__(512, 4) void k_attn(
    const unsigned short* __restrict__ Q,    // [4096][1024] bf16, pre-scaled by 0.125*log2e
    const unsigned short* __restrict__ Kb,   // [8][2048][64] bf16
    const unsigned short* __restrict__ Vt,   // [8][64][2048] f16
    unsigned short* __restrict__ Abuf) {     // [4096][1024] bf16
    __shared__ char smem[65536];             // K: [kvh][dbuf][8KB] @0, V: same @32768

    const int tid = threadIdx.x;
    const int lane = tid & 63, wid = tid >> 6;
    const int kvh = wid >> 2, qw = wid & 3;
    const int l31 = lane & 31, hi = lane >> 5;

    int wg = blockIdx.x;
    int swz = ((wg & 7) << 6) | (wg >> 3);   // XCD-aware (512 % 8 == 0)
    const int qt = swz & 15, head = (swz >> 4) & 15, b = swz >> 8;
    const int g = head >> 2;
    const size_t kvK = (size_t)(b * 4 + g) * 2048 * 64;
    const size_t kvV = (size_t)(b * 4 + g) * 64 * 2048;
    const int qrow0 = b * 2048 + qt * 128 + qw * 32;

    // Q fragments (B-operand): B[k = hi*8+j][col = q = l31], 32 q rows
    bfrag8 qf[4];
#pragma unroll
    for (int ks = 0; ks < 4; ++ks)
        qf[ks] = *reinterpret_cast<const bfrag8*>(
            Q + (size_t)(qrow0 + l31) * 1024 + head * 64 + ks * 16 + hi * 8);

    // staging: each wave stages 4 segs (2 of K-half, 2 of V-half) for its kvh
    const unsigned short* src[4];
    int ldsoff[4];
#pragma unroll
    for (int j = 0; j < 4; ++j) {
        int seg = (qw << 1) + (j & 1);
        bool isV = j >= 2;
        int p = seg * 1024 + lane * 16;
        int row = p >> 7;
        int sb = (p & 127) ^ ((row & 7) << 4);
        src[j] = !isV ? Kb + kvK + (size_t)(kvh * 64 + row) * 64 + (sb >> 1)
                      : Vt + kvV + (size_t)row * 2048 + kvh * 64 + (sb >> 1);
        ldsoff[j] = (isV ? 32768 : 0) + kvh * 16384 + seg * 1024;
    }

    facc16 o[2] = {};
    float psA = 0.f, psB = 0.f;

    // prologue: stage tile 0 into buf 0
#pragma unroll
    for (int j = 0; j < 4; ++j) gload_lds16(src[j], smem + ldsoff[j]);
    __syncthreads();

    for (int t = 0; t < 16; ++t) {
        const int cur = t & 1;
        if (t < 15) {
#pragma unroll
            for (int j = 0; j < 4; ++j)
                gload_lds16(src[j] + (size_t)(t + 1) * (j < 2 ? 128 * 64 : 128),
                            smem + ldsoff[j] + (cur ^ 1) * 8192);
        }
        const char* Kc = smem + kvh * 16384 + cur * 8192;
        const char* Vc = smem + 32768 + kvh * 16384 + cur * 8192;

        // S^T = K * Q^T : col = q = l31, row = kv = nt*32 + (r&3) + 8*(r>>2) + 4*hi
        facc16 s[2] = {};
        __builtin_amdgcn_s_setprio(1);
#pragma unroll
        for (int ks = 0; ks < 4; ++ks)
#pragma unroll
            for (int nt = 0; nt < 2; ++nt) {
                int row = nt * 32 + l31;
                int off = (row * 128 + ks * 32 + hi * 16) ^ ((row & 7) << 4);
                bfrag8 kf = *reinterpret_cast<const bfrag8*>(Kc + off);
                s[nt] = MFMA32B(kf, qf[ks], s[nt]);
            }
        __builtin_amdgcn_s_setprio(0);

        // p = exp2(s), in-register P^T assembly, PV
#pragma unroll
        for (int nt = 0; nt < 2; ++nt) {
#pragma unroll
            for (int e = 0; e < 16; e += 2) {
                float e0 = __builtin_amdgcn_exp2f(s[nt][e]);
                float e1 = __builtin_amdgcn_exp2f(s[nt][e + 1]);
                s[nt][e] = e0;
                s[nt][e + 1] = e1;
                psA += e0;
                psB += e1;
            }
#pragma unroll
            for (int kh = 0; kh < 2; ++kh) {
                const int ks = nt * 2 + kh;
                const int pb = kh * 2;
                unsigned a0 = pk2(s[nt][4 * pb + 0], s[nt][4 * pb + 1]);
                unsigned a1 = pk2(s[nt][4 * pb + 2], s[nt][4 * pb + 3]);
                unsigned b0 = pk2(s[nt][4 * pb + 4], s[nt][4 * pb + 5]);
                unsigned b1 = pk2(s[nt][4 * pb + 6], s[nt][4 * pb + 7]);
                asm("v_permlane32_swap_b32 %0, %1" : "+v"(a0), "+v"(b0));
                asm("v_permlane32_swap_b32 %0, %1" : "+v"(a1), "+v"(b1));
                union { unsigned u[4]; hfrag8 h; } pu;
                pu.u[0] = a0; pu.u[1] = a1; pu.u[2] = b0; pu.u[3] = b1;
                __builtin_amdgcn_s_setprio(1);
#pragma unroll
                for (int ot = 0; ot < 2; ++ot) {
                    int row = ot * 32 + l31;
                    int off = (row * 128 + ks * 32 + hi * 16) ^ ((row & 7) << 4);
                    hfrag8 vf = *reinterpret_cast<const hfrag8*>(Vc + off);
                    o[ot] = MFMA32H(vf, pu.h, o[ot]);
                }
                __builtin_amdgcn_s_setprio(0);
            }
        }
        __syncthreads();
    }

    // combine halves: kvh==1 waves dump O + psum to LDS; kvh==0 waves add
    float psum = psA + psB;
    float* cmO = (float*)smem;                 // 4 qw x 2048 f32 = 32 KB
    float* cmL = (float*)(smem + 32768);       // 4 qw x 64 f32
    if (kvh == 1) {
#pragma unroll
        for (int ot = 0; ot < 2; ++ot)
#pragma unroll
            for (int r = 0; r < 16; ++r)
                cmO[qw * 2048 + (ot * 16 + r) * 64 + lane] = o[ot][r];
        cmL[qw * 64 + lane] = psum;
    }
    __syncthreads();
    if (kvh == 0) {
#pragma unroll
        for (int ot = 0; ot < 2; ++ot)
#pragma unroll
            for (int r = 0; r < 16; ++r)
                o[ot][r] += cmO[qw * 2048 + (ot * 16 + r) * 64 + lane];
        psum += cmL[qw * 64 + lane];

        // epilogue: O^T row = d = (r&3)+8*(r>>2)+4*hi (per 8-block p), col = q = l31
        float l = psum + __shfl_xor(psum, 32, 64);
        float rl = 1.0f / l;
        int arow = qrow0 + l31;
#pragma unroll
        for (int ot = 0; ot < 2; ++ot)
#pragma unroll
            for (int p = 0; p < 4; ++p) {
                unsigned long long u = 0;
#pragma unroll
                for (int r = 0; r < 4; ++r)
                    u |= (unsigned long long)f2bf(o[ot][4 * p + r] * rl) << (16 * r);
                *reinterpret_cast<unsigned long long*>(
                    Abuf + (size_t)arow * 1024 + head * 64 + ot * 32 + p * 8 + hi * 4) = u;
            }
    }
}

// -------------------- launch --------------------

extern "C" void kernel_launch(void* const* d_in, const int* in_sizes, int n_in,
                              void* d_out, int out_size, void* d_ws, size_t ws_size,
                              hipStream_t stream) {
    const float* X = (const float*)d_in[0];
    const float* Wq = (const float*)d_in[1];
    const float* Wk = (const float*)d_in[2];
    const float* Wv = (const float*)d_in[3];
    const float* Wpost = (const float*)d_in[4];
    float* Out = (float*)d_out;

    unsigned short* Xb = (unsigned short*)d_ws;          // 4096*1024 bf16
    unsigned short* Wqkvt = Xb + 4096 * 1024;            // 1536*1024 bf16
    unsigned short* Wpt = Wqkvt + 1536 * 1024;           // 1024*1024 bf16
    unsigned short* Qb = Wpt + 1024 * 1024;              // 4096*1024 bf16 (pre-scaled)
    unsigned short* Kbuf = Qb + 4096 * 1024;             // 8*2048*64 bf16
    unsigned short* Vtbuf = Kbuf + 8 * 2048 * 64;        // 8*64*2048 f16
    unsigned short* Abuf = Vtbuf + 8 * 2048 * 64;        // 4096*1024 bf16

    k_prep<<<6656, 256, 0, stream>>>(X, Wq, Wk, Wv, Wpost, Xb, Wqkvt, Wpt);

    k_gemm_bt<0><<<dim3(24, 32), 512, 0, stream>>>(Xb, Wqkvt, 4096, 1536, 1024,
                                                   Qb, Kbuf, Vtbuf, nullptr, nullptr);

    k_attn<<<512, 512, 0, stream>>>(Qb, Kbuf, Vtbuf, Abuf);

    k_gemm_bt<1><<<dim3(16, 32), 512, 0, stream>>>(Abuf, Wpt, 4096, 1024, 1024,
                                                   nullptr, nullptr, nullptr, X, Out);
}